// Round 1
// baseline (53.838 us; speedup 1.0000x reference)
//
#include <hip/hip_runtime.h>
#include <hip/hip_bf16.h>

// ---------------------------------------------------------------------------
// QuantumNeuralNetwork: out[b][q] = <psi_b| U^dag Z_q U |psi_b>,
// psi_b = x_b / ||x_b||, U = fixed 7-qubit circuit from weights.
//
// Strategy:
//   Kernel 1: build W = [Re(U); Im(U)] (2 planes of 128x128 bf16) in d_ws by
//             simulating each column U|k> (one wave per column, 2 amps/lane).
//   Kernel 2: z_q[b] = (sum_s sign * p_s) / (sum_s p_s),   p_s = re^2 + im^2,
//             [re|im] = W @ x_b   (unnormalized; unitarity => total = ||x||^2)
//             done as MFMA 32x32x16 bf16 with W in registers, x from global.
// ---------------------------------------------------------------------------

typedef __attribute__((ext_vector_type(8)))  short short8;   // 8 x bf16
typedef __attribute__((ext_vector_type(16))) float f32x16;   // 32x32 acc

static __device__ __forceinline__ short f2bf(float f) {
  __bf16 h = (__bf16)f;                     // RNE convert (v_cvt_pk_bf16_f32)
  return __builtin_bit_cast(short, h);
}

// ------------------------------- kernel 1 ----------------------------------
// grid = 128 blocks (one column k each), block = 64 threads (one wave).
// Lane l holds amplitudes for states s = 2l, 2l+1 (bit0 of s is in-lane).
// Wire q <-> s-bit (6-q). s-bits 1..6 <-> lane bits 0..5.
__global__ void qnn_build_w(const float* __restrict__ wts,
                            short* __restrict__ W) {
  const int k = blockIdx.x;
  const int l = threadIdx.x;

  float c0r = (2 * l     == k) ? 1.f : 0.f, c0i = 0.f;
  float c1r = (2 * l + 1 == k) ? 1.f : 0.f, c1i = 0.f;

  for (int layer = 0; layer < 2; ++layer) {
    // fused rotations G = Rz * Ry * Rx per qubit
    for (int q = 0; q < 7; ++q) {
      const float t0 = 0.5f * wts[(layer * 7 + q) * 3 + 0];
      const float t1 = 0.5f * wts[(layer * 7 + q) * 3 + 1];
      const float t2 = 0.5f * wts[(layer * 7 + q) * 3 + 2];
      const float cx = cosf(t0), sx = sinf(t0);
      const float cy = cosf(t1), sy = sinf(t1);
      const float cz = cosf(t2), sz = sinf(t2);
      // M = Ry*Rx
      const float m00r =  cy * cx, m00i =  sy * sx;
      const float m01r = -sy * cx, m01i = -cy * sx;
      const float m10r =  sy * cx, m10i = -cy * sx;
      const float m11r =  cy * cx, m11i = -sy * sx;
      // G = Rz*M : row0 *= (cz - i sz), row1 *= (cz + i sz)
      const float g00r = m00r * cz + m00i * sz, g00i = m00i * cz - m00r * sz;
      const float g01r = m01r * cz + m01i * sz, g01i = m01i * cz - m01r * sz;
      const float g10r = m10r * cz - m10i * sz, g10i = m10i * cz + m10r * sz;
      const float g11r = m11r * cz - m11i * sz, g11i = m11i * cz + m11r * sz;

      const int b = 6 - q;  // s-bit this gate acts on
      if (b == 0) {
        // in-lane butterfly (c0, c1)
        const float n0r = g00r*c0r - g00i*c0i + g01r*c1r - g01i*c1i;
        const float n0i = g00r*c0i + g00i*c0r + g01r*c1i + g01i*c1r;
        const float n1r = g10r*c0r - g10i*c0i + g11r*c1r - g11i*c1i;
        const float n1i = g10r*c0i + g10i*c0r + g11r*c1i + g11i*c1r;
        c0r = n0r; c0i = n0i; c1r = n1r; c1i = n1i;
      } else {
        const int xm  = 1 << (b - 1);          // lane xor mask
        const int myb = (l >> (b - 1)) & 1;    // my value of bit b
        const float p0r = __shfl_xor(c0r, xm), p0i = __shfl_xor(c0i, xm);
        const float p1r = __shfl_xor(c1r, xm), p1i = __shfl_xor(c1i, xm);
        const float gar = myb ? g11r : g00r, gai = myb ? g11i : g00i;
        const float gbr = myb ? g10r : g01r, gbi = myb ? g10i : g01i;
        const float n0r = gar*c0r - gai*c0i + gbr*p0r - gbi*p0i;
        const float n0i = gar*c0i + gai*c0r + gbr*p0i + gbi*p0r;
        const float n1r = gar*c1r - gai*c1i + gbr*p1r - gbi*p1i;
        const float n1i = gar*c1i + gai*c1r + gbr*p1i + gbi*p1r;
        c0r = n0r; c0i = n0i; c1r = n1r; c1i = n1i;
      }
    }
    // CNOT ring: (c,t) = (q, (q+1)%7), control bit bc=6-q, target bt=6-t
    #pragma unroll
    for (int q = 0; q < 7; ++q) {
      const int bc = 6 - q;
      const int bt = 6 - ((q + 1) % 7);
      if (bt == 0) {                       // (bc=1, bt=0): in-lane swap
        if (l & 1) { float tr=c0r, ti=c0i; c0r=c1r; c0i=c1i; c1r=tr; c1i=ti; }
      } else if (bc == 0) {                // (0,6): amps with s-bit0=1 swap
        c1r = __shfl_xor(c1r, 32);
        c1i = __shfl_xor(c1i, 32);
      } else {                             // cross-lane conditional swap
        const int xm = 1 << (bt - 1);
        const float p0r = __shfl_xor(c0r, xm), p0i = __shfl_xor(c0i, xm);
        const float p1r = __shfl_xor(c1r, xm), p1i = __shfl_xor(c1i, xm);
        if ((l >> (bc - 1)) & 1) { c0r=p0r; c0i=p0i; c1r=p1r; c1i=p1i; }
      }
    }
  }

  // W layout: plane Re [s][k] (128*128 bf16), then plane Im at +16384 elems
  W[(2 * l)     * 128 + k]         = f2bf(c0r);
  W[(2 * l + 1) * 128 + k]         = f2bf(c1r);
  W[16384 + (2 * l)     * 128 + k] = f2bf(c0i);
  W[16384 + (2 * l + 1) * 128 + k] = f2bf(c1i);
}

// ------------------------------- kernel 2 ----------------------------------
// Block = 256 threads (4 waves), tile = 32 batch rows.
// Wave wv owns states s in [32wv, 32wv+32): acc0 = Re, acc1 = Im (A operand
// slices of W, preloaded to 64 VGPRs). B operand = x rows, straight from
// global (4 waves read identical addresses -> L1 dedupe).
// MFMA 32x32x16: A lane l: row=l&31, k=8*(l>>5)+[0,8); B lane l: col=l&31,
// same k; D: col=lane&31, m=(reg&3)+8*(reg>>2)+4*(lane>>5).
// s = 32*wv + m; s-bits: b0=reg&1, b1=(reg>>1)&1, b2=lane>>5, b3=(reg>>2)&1,
// b4=(reg>>3)&1, b5=wv&1, b6=wv>>1.  z_q uses s-bit (6-q).
__global__ __launch_bounds__(256, 2) void qnn_main(
    const float* __restrict__ x, const short* __restrict__ W,
    float* __restrict__ out, int ntiles) {
  const int tid = threadIdx.x;
  const int l   = tid & 63;
  const int wv  = tid >> 6;
  const int col = l & 31;
  const int h   = l >> 5;

  __shared__ float red[4][32][6];

  // Preload this wave's W slice: 16 frags of 8 bf16 = 64 VGPRs.
  short8 A0[8], A1[8];
  {
    const int arow = 32 * wv + col;           // state index s
    #pragma unroll
    for (int j = 0; j < 8; ++j) {
      const int off = arow * 128 + j * 16 + h * 8;
      A0[j] = *reinterpret_cast<const short8*>(W + off);
      A1[j] = *reinterpret_cast<const short8*>(W + 16384 + off);
    }
  }

  for (int tile = blockIdx.x; tile < ntiles; tile += gridDim.x) {
    const float* xr = x + (size_t)(tile * 32 + col) * 128 + h * 8;

    f32x16 acc0 = {0.f,0.f,0.f,0.f,0.f,0.f,0.f,0.f,
                   0.f,0.f,0.f,0.f,0.f,0.f,0.f,0.f};
    f32x16 acc1 = {0.f,0.f,0.f,0.f,0.f,0.f,0.f,0.f,
                   0.f,0.f,0.f,0.f,0.f,0.f,0.f,0.f};

    #pragma unroll
    for (int j = 0; j < 8; ++j) {
      const float4 f0 = *reinterpret_cast<const float4*>(xr + j * 16);
      const float4 f1 = *reinterpret_cast<const float4*>(xr + j * 16 + 4);
      short8 bfr;
      bfr[0] = f2bf(f0.x); bfr[1] = f2bf(f0.y);
      bfr[2] = f2bf(f0.z); bfr[3] = f2bf(f0.w);
      bfr[4] = f2bf(f1.x); bfr[5] = f2bf(f1.y);
      bfr[6] = f2bf(f1.z); bfr[7] = f2bf(f1.w);
      acc0 = __builtin_amdgcn_mfma_f32_32x32x16_bf16(A0[j], bfr, acc0, 0, 0, 0);
      acc1 = __builtin_amdgcn_mfma_f32_32x32x16_bf16(A1[j], bfr, acc1, 0, 0, 0);
    }

    // p = re^2 + im^2 per (reg) ; Walsh tree over reg-bits -> T, u_b0..u_b4
    float aS[8], aD[8];
    #pragma unroll
    for (int i = 0; i < 8; ++i) {
      const float pe = acc0[2*i]   * acc0[2*i]   + acc1[2*i]   * acc1[2*i];
      const float po = acc0[2*i+1] * acc0[2*i+1] + acc1[2*i+1] * acc1[2*i+1];
      aS[i] = pe + po;   // sum over b0
      aD[i] = pe - po;   // (b0=0) - (b0=1)
    }
    float bS[4], bD[4];
    #pragma unroll
    for (int i = 0; i < 4; ++i) {
      bS[i] = aS[2*i] + aS[2*i+1];
      bD[i] = aS[2*i] - aS[2*i+1];
    }
    float u0 = ((aD[0]+aD[1]) + (aD[2]+aD[3])) + ((aD[4]+aD[5]) + (aD[6]+aD[7]));
    float u1 = (bD[0] + bD[1]) + (bD[2] + bD[3]);
    const float cS0 = bS[0] + bS[1], cD0 = bS[0] - bS[1];
    const float cS1 = bS[2] + bS[3], cD1 = bS[2] - bS[3];
    float u3 = cD0 + cD1;
    float u4 = cS0 - cS1;
    float T  = cS0 + cS1;

    // combine across lane halves (s-bit b2)
    const float Tp = __shfl_xor(T, 32);
    const float u2 = h ? (Tp - T) : (T - Tp);
    T += Tp;
    u0 += __shfl_xor(u0, 32);
    u1 += __shfl_xor(u1, 32);
    u3 += __shfl_xor(u3, 32);
    u4 += __shfl_xor(u4, 32);

    if (h == 0) {
      red[wv][col][0] = T;
      red[wv][col][1] = u0;
      red[wv][col][2] = u1;
      red[wv][col][3] = u2;
      red[wv][col][4] = u3;
      red[wv][col][5] = u4;
    }
    __syncthreads();

    // combine across waves (s-bits b5, b6) and write 7 outputs per row
    if (tid < 32) {
      const int c = tid;
      const float T0 = red[0][c][0], T1 = red[1][c][0];
      const float T2 = red[2][c][0], T3 = red[3][c][0];
      const float sT  = (T0 + T1) + (T2 + T3);
      const float inv = 1.0f / sT;               // == 1/||x||^2 (unitarity)
      const float z0 = (T0 + T1) - (T2 + T3);                       // bit6
      const float z1 = (T0 - T1) + (T2 - T3);                       // bit5
      const float z2 = (red[0][c][5]+red[1][c][5]) + (red[2][c][5]+red[3][c][5]); // u4
      const float z3 = (red[0][c][4]+red[1][c][4]) + (red[2][c][4]+red[3][c][4]); // u3
      const float z4 = (red[0][c][3]+red[1][c][3]) + (red[2][c][3]+red[3][c][3]); // u2
      const float z5 = (red[0][c][2]+red[1][c][2]) + (red[2][c][2]+red[3][c][2]); // u1
      const float z6 = (red[0][c][1]+red[1][c][1]) + (red[2][c][1]+red[3][c][1]); // u0
      float* o = out + (size_t)(tile * 32 + c) * 7;
      o[0] = z0 * inv; o[1] = z1 * inv; o[2] = z2 * inv; o[3] = z3 * inv;
      o[4] = z4 * inv; o[5] = z5 * inv; o[6] = z6 * inv;
    }
    __syncthreads();
  }
}

// ------------------------------- launcher ----------------------------------
extern "C" void kernel_launch(void* const* d_in, const int* in_sizes, int n_in,
                              void* d_out, int out_size, void* d_ws, size_t ws_size,
                              hipStream_t stream) {
  const float* x   = (const float*)d_in[0];
  const float* wts = (const float*)d_in[1];
  float* out = (float*)d_out;
  short* W   = (short*)d_ws;                 // 2 * 128*128 bf16 = 64 KiB

  const int B      = in_sizes[0] / 128;
  const int ntiles = B / 32;

  qnn_build_w<<<128, 64, 0, stream>>>(wts, W);

  const int blocks = ntiles < 1024 ? ntiles : 1024;
  qnn_main<<<blocks, 256, 0, stream>>>(x, W, out, ntiles);
}

// Round 2
// 31.805 us; speedup vs baseline: 1.6928x; 1.6928x over previous
//
#include <hip/hip_runtime.h>
#include <hip/hip_bf16.h>

// ---------------------------------------------------------------------------
// QuantumNeuralNetwork: out[b][q] = <psi_b| U^dag Z_q U |psi_b>.
// Kernel 1: build W = [Re(U); Im(U)] (128x128 bf16 x2) in d_ws.
// Kernel 2: per 64-row tile: stage x as bf16 into XOR-swizzled LDS (each
//           thread loads a disjoint slice, prefetched 1 iter ahead), then
//           4 waves x 32 states MFMA, Walsh-tree epilogue, z = signed/total.
// ---------------------------------------------------------------------------

typedef __attribute__((ext_vector_type(8)))  short short8;   // 8 x bf16
typedef __attribute__((ext_vector_type(16))) float f32x16;   // 32x32 acc

static __device__ __forceinline__ short f2bf(float f) {
  __bf16 h = (__bf16)f;
  return __builtin_bit_cast(short, h);
}

// ------------------------------- kernel 1 ----------------------------------
// 128 blocks (one column k each) x 64 threads. Lane l holds states 2l, 2l+1.
__global__ void qnn_build_w(const float* __restrict__ wts,
                            short* __restrict__ W) {
  const int k = blockIdx.x;
  const int l = threadIdx.x;

  float c0r = (2 * l     == k) ? 1.f : 0.f, c0i = 0.f;
  float c1r = (2 * l + 1 == k) ? 1.f : 0.f, c1i = 0.f;

  for (int layer = 0; layer < 2; ++layer) {
    for (int q = 0; q < 7; ++q) {
      const float t0 = 0.5f * wts[(layer * 7 + q) * 3 + 0];
      const float t1 = 0.5f * wts[(layer * 7 + q) * 3 + 1];
      const float t2 = 0.5f * wts[(layer * 7 + q) * 3 + 2];
      const float cx = cosf(t0), sx = sinf(t0);
      const float cy = cosf(t1), sy = sinf(t1);
      const float cz = cosf(t2), sz = sinf(t2);
      const float m00r =  cy * cx, m00i =  sy * sx;
      const float m01r = -sy * cx, m01i = -cy * sx;
      const float m10r =  sy * cx, m10i = -cy * sx;
      const float m11r =  cy * cx, m11i = -sy * sx;
      const float g00r = m00r * cz + m00i * sz, g00i = m00i * cz - m00r * sz;
      const float g01r = m01r * cz + m01i * sz, g01i = m01i * cz - m01r * sz;
      const float g10r = m10r * cz - m10i * sz, g10i = m10i * cz + m10r * sz;
      const float g11r = m11r * cz - m11i * sz, g11i = m11i * cz + m11r * sz;

      const int b = 6 - q;
      if (b == 0) {
        const float n0r = g00r*c0r - g00i*c0i + g01r*c1r - g01i*c1i;
        const float n0i = g00r*c0i + g00i*c0r + g01r*c1i + g01i*c1r;
        const float n1r = g10r*c0r - g10i*c0i + g11r*c1r - g11i*c1i;
        const float n1i = g10r*c0i + g10i*c0r + g11r*c1i + g11i*c1r;
        c0r = n0r; c0i = n0i; c1r = n1r; c1i = n1i;
      } else {
        const int xm  = 1 << (b - 1);
        const int myb = (l >> (b - 1)) & 1;
        const float p0r = __shfl_xor(c0r, xm), p0i = __shfl_xor(c0i, xm);
        const float p1r = __shfl_xor(c1r, xm), p1i = __shfl_xor(c1i, xm);
        const float gar = myb ? g11r : g00r, gai = myb ? g11i : g00i;
        const float gbr = myb ? g10r : g01r, gbi = myb ? g10i : g01i;
        const float n0r = gar*c0r - gai*c0i + gbr*p0r - gbi*p0i;
        const float n0i = gar*c0i + gai*c0r + gbr*p0i + gbi*p0r;
        const float n1r = gar*c1r - gai*c1i + gbr*p1r - gbi*p1i;
        const float n1i = gar*c1i + gai*c1r + gbr*p1i + gbi*p1r;
        c0r = n0r; c0i = n0i; c1r = n1r; c1i = n1i;
      }
    }
    #pragma unroll
    for (int q = 0; q < 7; ++q) {
      const int bc = 6 - q;
      const int bt = 6 - ((q + 1) % 7);
      if (bt == 0) {
        if (l & 1) { float tr=c0r, ti=c0i; c0r=c1r; c0i=c1i; c1r=tr; c1i=ti; }
      } else if (bc == 0) {
        c1r = __shfl_xor(c1r, 32);
        c1i = __shfl_xor(c1i, 32);
      } else {
        const int xm = 1 << (bt - 1);
        const float p0r = __shfl_xor(c0r, xm), p0i = __shfl_xor(c0i, xm);
        const float p1r = __shfl_xor(c1r, xm), p1i = __shfl_xor(c1i, xm);
        if ((l >> (bc - 1)) & 1) { c0r=p0r; c0i=p0i; c1r=p1r; c1i=p1i; }
      }
    }
  }

  W[(2 * l)     * 128 + k]         = f2bf(c0r);
  W[(2 * l + 1) * 128 + k]         = f2bf(c1r);
  W[16384 + (2 * l)     * 128 + k] = f2bf(c0i);
  W[16384 + (2 * l + 1) * 128 + k] = f2bf(c1i);
}

// ------------------------------- kernel 2 ----------------------------------
// 256 threads (4 waves). 64 rows per iteration. Wave wv owns states
// [32wv, 32wv+32) (A slice in 64 VGPRs). x tile staged bf16 in LDS, chunk
// (16B) swizzled: stored index = r*16 + (q ^ (r&7))  (conflict-free for both
// the per-row strided B-frag ds_read_b128 and the staging ds_write_b128).
// Staging loads for iter t+1 are issued during iter t (T14 split); barriers
// are raw s_barrier + lgkmcnt fences so vmcnt stays in flight across them.
__global__ __launch_bounds__(256, 2) void qnn_main(
    const float* __restrict__ x, const short* __restrict__ W,
    float* __restrict__ out, int niter, int stride) {
  const int tid = threadIdx.x;
  const int l   = tid & 63;
  const int wv  = tid >> 6;
  const int col = l & 31;
  const int h   = l >> 5;

  __shared__ short8 xb[1024];        // 64 rows x 16 chunks (swizzled), 16 KiB
  __shared__ float  red[4][64][6];   // 6 KiB

  // Preload this wave's W slice: 16 frags of 8 bf16 = 64 VGPRs.
  short8 A0[8], A1[8];
  #pragma unroll
  for (int j = 0; j < 8; ++j) {
    const int off = (32 * wv + col) * 128 + j * 16 + h * 8;
    A0[j] = *reinterpret_cast<const short8*>(W + off);
    A1[j] = *reinterpret_cast<const short8*>(W + 16384 + off);
  }

  float4 fa[4], fb[4];
  int t = blockIdx.x;

  // ---- prologue: load tile t -> regs; cvt -> LDS; issue loads for t+stride
  #pragma unroll
  for (int i = 0; i < 4; ++i) {
    const int p = i * 256 + tid;
    const int r = p >> 4, q = p & 15;
    const float* gp = x + (size_t)(t * 64 + r) * 128 + q * 8;
    fa[i] = *reinterpret_cast<const float4*>(gp);
    fb[i] = *reinterpret_cast<const float4*>(gp + 4);
  }
  #pragma unroll
  for (int i = 0; i < 4; ++i) {
    const int p = i * 256 + tid;
    const int r = p >> 4, q = p & 15;
    short8 c;
    c[0]=f2bf(fa[i].x); c[1]=f2bf(fa[i].y); c[2]=f2bf(fa[i].z); c[3]=f2bf(fa[i].w);
    c[4]=f2bf(fb[i].x); c[5]=f2bf(fb[i].y); c[6]=f2bf(fb[i].z); c[7]=f2bf(fb[i].w);
    xb[r * 16 + (q ^ (r & 7))] = c;
  }
  if (t + stride < niter) {
    #pragma unroll
    for (int i = 0; i < 4; ++i) {
      const int p = i * 256 + tid;
      const int r = p >> 4, q = p & 15;
      const float* gp = x + (size_t)((t + stride) * 64 + r) * 128 + q * 8;
      fa[i] = *reinterpret_cast<const float4*>(gp);
      fb[i] = *reinterpret_cast<const float4*>(gp + 4);
    }
  }
  asm volatile("s_waitcnt lgkmcnt(0)" ::: "memory");
  __builtin_amdgcn_s_barrier();
  asm volatile("" ::: "memory");

  for (; t < niter; t += stride) {
    // ---- compute: 16 ds_read_b128 + 32 MFMA per wave
    f32x16 acc0[2], acc1[2];
    #pragma unroll
    for (int g = 0; g < 2; ++g)
      #pragma unroll
      for (int e = 0; e < 16; ++e) { acc0[g][e] = 0.f; acc1[g][e] = 0.f; }

    #pragma unroll
    for (int g = 0; g < 2; ++g) {
      const int r = g * 32 + col;
      #pragma unroll
      for (int j = 0; j < 8; ++j) {
        const int q = j * 2 + h;
        const short8 bfr = xb[r * 16 + (q ^ (r & 7))];
        acc0[g] = __builtin_amdgcn_mfma_f32_32x32x16_bf16(A0[j], bfr, acc0[g], 0, 0, 0);
        acc1[g] = __builtin_amdgcn_mfma_f32_32x32x16_bf16(A1[j], bfr, acc1[g], 0, 0, 0);
      }
    }

    // ---- epilogue: p = re^2+im^2, Walsh tree over s-bits, partial -> red
    #pragma unroll
    for (int g = 0; g < 2; ++g) {
      float aS[8], aD[8];
      #pragma unroll
      for (int i = 0; i < 8; ++i) {
        const float pe = acc0[g][2*i]   * acc0[g][2*i]   + acc1[g][2*i]   * acc1[g][2*i];
        const float po = acc0[g][2*i+1] * acc0[g][2*i+1] + acc1[g][2*i+1] * acc1[g][2*i+1];
        aS[i] = pe + po;
        aD[i] = pe - po;
      }
      float bS[4], bD[4];
      #pragma unroll
      for (int i = 0; i < 4; ++i) {
        bS[i] = aS[2*i] + aS[2*i+1];
        bD[i] = aS[2*i] - aS[2*i+1];
      }
      float u0 = ((aD[0]+aD[1]) + (aD[2]+aD[3])) + ((aD[4]+aD[5]) + (aD[6]+aD[7]));
      float u1 = (bD[0] + bD[1]) + (bD[2] + bD[3]);
      const float cS0 = bS[0] + bS[1], cD0 = bS[0] - bS[1];
      const float cS1 = bS[2] + bS[3], cD1 = bS[2] - bS[3];
      float u3 = cD0 + cD1;
      float u4 = cS0 - cS1;
      float T  = cS0 + cS1;

      const float Tp = __shfl_xor(T, 32);
      const float u2 = h ? (Tp - T) : (T - Tp);
      T += Tp;
      u0 += __shfl_xor(u0, 32);
      u1 += __shfl_xor(u1, 32);
      u3 += __shfl_xor(u3, 32);
      u4 += __shfl_xor(u4, 32);

      if (h == 0) {
        red[wv][g * 32 + col][0] = T;
        red[wv][g * 32 + col][1] = u0;
        red[wv][g * 32 + col][2] = u1;
        red[wv][g * 32 + col][3] = u2;
        red[wv][g * 32 + col][4] = u3;
        red[wv][g * 32 + col][5] = u4;
      }
    }

    asm volatile("s_waitcnt lgkmcnt(0)" ::: "memory");
    __builtin_amdgcn_s_barrier();          // red ready; xb fully consumed
    asm volatile("" ::: "memory");

    // ---- combine across waves, write 7 outputs for 64 rows
    if (tid < 64) {
      const int c = tid;
      const float T0 = red[0][c][0], T1 = red[1][c][0];
      const float T2 = red[2][c][0], T3 = red[3][c][0];
      const float sT  = (T0 + T1) + (T2 + T3);
      const float inv = 1.0f / sT;          // == 1/||x||^2 (unitarity)
      const float z0 = (T0 + T1) - (T2 + T3);
      const float z1 = (T0 - T1) + (T2 - T3);
      const float z2 = (red[0][c][5]+red[1][c][5]) + (red[2][c][5]+red[3][c][5]);
      const float z3 = (red[0][c][4]+red[1][c][4]) + (red[2][c][4]+red[3][c][4]);
      const float z4 = (red[0][c][3]+red[1][c][3]) + (red[2][c][3]+red[3][c][3]);
      const float z5 = (red[0][c][2]+red[1][c][2]) + (red[2][c][2]+red[3][c][2]);
      const float z6 = (red[0][c][1]+red[1][c][1]) + (red[2][c][1]+red[3][c][1]);
      float* o = out + (size_t)(t * 64 + c) * 7;
      o[0] = z0 * inv; o[1] = z1 * inv; o[2] = z2 * inv; o[3] = z3 * inv;
      o[4] = z4 * inv; o[5] = z5 * inv; o[6] = z6 * inv;
    }

    // ---- staging: cvt regs (tile t+stride) -> xb, issue loads for t+2s
    if (t + stride < niter) {
      #pragma unroll
      for (int i = 0; i < 4; ++i) {
        const int p = i * 256 + tid;
        const int r = p >> 4, q = p & 15;
        short8 c;
        c[0]=f2bf(fa[i].x); c[1]=f2bf(fa[i].y); c[2]=f2bf(fa[i].z); c[3]=f2bf(fa[i].w);
        c[4]=f2bf(fb[i].x); c[5]=f2bf(fb[i].y); c[6]=f2bf(fb[i].z); c[7]=f2bf(fb[i].w);
        xb[r * 16 + (q ^ (r & 7))] = c;
      }
      if (t + 2 * stride < niter) {
        #pragma unroll
        for (int i = 0; i < 4; ++i) {
          const int p = i * 256 + tid;
          const int r = p >> 4, q = p & 15;
          const float* gp = x + (size_t)((t + 2 * stride) * 64 + r) * 128 + q * 8;
          fa[i] = *reinterpret_cast<const float4*>(gp);
          fb[i] = *reinterpret_cast<const float4*>(gp + 4);
        }
      }
    }
    asm volatile("s_waitcnt lgkmcnt(0)" ::: "memory");
    __builtin_amdgcn_s_barrier();          // xb ready for next compute
    asm volatile("" ::: "memory");
  }
}

// ------------------------------- launcher ----------------------------------
extern "C" void kernel_launch(void* const* d_in, const int* in_sizes, int n_in,
                              void* d_out, int out_size, void* d_ws, size_t ws_size,
                              hipStream_t stream) {
  const float* x   = (const float*)d_in[0];
  const float* wts = (const float*)d_in[1];
  float* out = (float*)d_out;
  short* W   = (short*)d_ws;               // 2 * 128*128 bf16 = 64 KiB

  const int B     = in_sizes[0] / 128;
  const int niter = B / 64;
  const int grid  = niter < 512 ? niter : 512;

  qnn_build_w<<<128, 64, 0, stream>>>(wts, W);
  qnn_main<<<grid, 256, 0, stream>>>(x, W, out, niter, grid);
}